// Round 14
// baseline (400.375 us; speedup 1.0000x reference)
//
#include <hip/hip_runtime.h>
#include <hip/hip_fp16.h>

#define P 10
#define D 1024
#define NROWS 16384

typedef float nfloat4 __attribute__((ext_vector_type(4)));   // clang-native for nontemporal builtins

// ---------------------------------------------------------------------------
// Column mapping (r4 keeper):
//   k = e_hi*256 + lane*4 + e_lo,  e = e_hi*4 + e_lo,  e in [0,16), lane in [0,64)
//   stage j flips bit j of k:
//     j=0,1 -> e bits 0,1 (intra) | j=2..7 -> lane bit j-2 (shfl) | j=8,9 -> e bits 2,3 (intra)
// Pair-packed f16 coef table (r13): ctab[j*512 + p*64 + lane] = uint4
//   {h2(uA), h2(vA), h2(uB), h2(vB)} for the stage's butterfly pair p.
// psi folded into stage-9 coefs.
//
// THIS ROUND: R=1 — ONE row per wave, __launch_bounds__(256,8) pinning
// VGPR <= 64 -> 32 waves/CU occupancy band (2x all prior rounds). Chip-wide
// coef VMEM doubles, but r10/r13 proved that stream has slack; this trades
// slack bandwidth for latency hiding (the one untested axis).
// ---------------------------------------------------------------------------
__device__ __forceinline__ float4 coef_uv(int j, int e, int lane,
                                          const float* __restrict__ theta,
                                          const float* __restrict__ phi,
                                          const float* __restrict__ psi) {
    int k = ((e >> 2) << 8) | (lane << 2) | (e & 3);
    int b = (k >> j) & 1;
    unsigned lowmask = (1u << j) - 1u;
    unsigned m = ((unsigned)k & lowmask) | (((unsigned)k >> 1) & ~lowmask); // delete bit j
    float th = theta[j * (D / 2) + m];
    float ph = phi[j * (D / 2) + m];
    float h = th * 0.5f;
    float s1 = sinf(h), c1 = cosf(h);
    float s2 = sinf(h + ph), c2 = cosf(h + ph);
    float ur, ui, vr, vi;
    if (b) { ur =  s1 * s1; vr = -c1 * s2; ui = -c1 * s1; vi = c1 * c2; }
    else   { ur = -s1 * s2; vr = -c1 * s1; ui =  s1 * c2; vi = c1 * c1; }
    if (j == P - 1) {
        float ps = psi[k];
        float cp = cosf(ps), sp = sinf(ps);
        float ur2 = cp * ur - sp * ui, ui2 = sp * ur + cp * ui;
        float vr2 = cp * vr - sp * vi, vi2 = sp * vr + cp * vi;
        ur = ur2; ui = ui2; vr = vr2; vi = vi2;
    }
    return make_float4(ur, ui, vr, vi);
}

__device__ __forceinline__ unsigned packh2(float x, float y) {
    __half2 h = __floats2half2_rn(x, y);
    return *reinterpret_cast<unsigned*>(&h);
}

__global__ void coef_kernel(const float* __restrict__ theta,
                            const float* __restrict__ phi,
                            const float* __restrict__ psi,
                            uint4* __restrict__ ctab) {
    int idx = blockIdx.x * blockDim.x + threadIdx.x;
    if (idx >= P * 512) return;
    int j = idx >> 9;
    int slot = idx & 511;
    int p = slot >> 6;
    int lane = slot & 63;
    int eA, eB;
    if (j >= 2 && j <= 7) {                 // shfl stage: bundle (2p, 2p+1)
        eA = 2 * p; eB = 2 * p + 1;
    } else {                                // intra stage: butterfly pair
        int PM = (j == 0) ? 1 : (j == 1) ? 2 : (j == 8) ? 4 : 8;
        eA = (p & (PM - 1)) | ((p & ~(PM - 1)) << 1);
        eB = eA | PM;
    }
    float4 a = coef_uv(j, eA, lane, theta, phi, psi);
    float4 b = coef_uv(j, eB, lane, theta, phi, psi);
    uint4 w;
    w.x = packh2(a.x, a.y);
    w.y = packh2(a.z, a.w);
    w.z = packh2(b.x, b.y);
    w.w = packh2(b.z, b.w);
    ctab[idx] = w;
}

__device__ __forceinline__ void unp2(unsigned u, float& x, float& y) {
    __half2 h = *reinterpret_cast<__half2*>(&u);
    x = __low2float(h); y = __high2float(h);
}

// ---------------------------------------------------------------------------
// Intra-thread butterfly stage (single row): partner differs in bit PM of e.
// ---------------------------------------------------------------------------
template <int PM>
__device__ __forceinline__ void stage_intra(float (&re)[16], float (&im)[16],
                                            const uint4* cj) {
#pragma unroll
    for (int e0 = 0; e0 < 16; ++e0) {
        if (e0 & PM) continue;
        const int e1 = e0 | PM;
        const int p = (e0 & (PM - 1)) | ((e0 >> 1) & ~(PM - 1));  // delete bit log2(PM)
        uint4 w = cj[p * 64];
        float u0r, u0i, v0r, v0i, u1r, u1i, v1r, v1i;
        unp2(w.x, u0r, u0i); unp2(w.y, v0r, v0i);
        unp2(w.z, u1r, u1i); unp2(w.w, v1r, v1i);
        float ar0 = re[e0], ai0 = im[e0], ar1 = re[e1], ai1 = im[e1];
        re[e0] = u0r * ar0 - u0i * ai0 + v0r * ar1 - v0i * ai1;
        im[e0] = u0r * ai0 + u0i * ar0 + v0r * ai1 + v0i * ar1;
        re[e1] = u1r * ar1 - u1i * ai1 + v1r * ar0 - v1i * ai0;
        im[e1] = u1r * ai1 + u1i * ar1 + v1r * ai0 + v1i * ar0;
    }
}

// ---------------------------------------------------------------------------
// Cross-lane butterfly stage (single row): partner differs in lane bit MASK.
// ---------------------------------------------------------------------------
template <int MASK>
__device__ __forceinline__ void stage_shfl(float (&re)[16], float (&im)[16],
                                           const uint4* cj) {
#pragma unroll
    for (int p = 0; p < 8; ++p) {
        uint4 w = cj[p * 64];
#pragma unroll
        for (int h = 0; h < 2; ++h) {
            const int e = 2 * p + h;
            float ur, ui, vr, vi;
            unp2(h == 0 ? w.x : w.z, ur, ui);
            unp2(h == 0 ? w.y : w.w, vr, vi);
            float sre = __shfl_xor(re[e], MASK);
            float sim = __shfl_xor(im[e], MASK);
            float nre = ur * re[e] - ui * im[e] + vr * sre - vi * sim;
            float nim = ur * im[e] + ui * re[e] + vr * sim + vi * sre;
            re[e] = nre; im[e] = nim;
        }
    }
}

__global__ __launch_bounds__(256, 8) void fft_kernel(const float* __restrict__ X,
                                                     const uint4* __restrict__ ctab,
                                                     float* __restrict__ out) {
    const int lane = threadIdx.x & 63;
    const int wave = threadIdx.x >> 6;
    const long row = (long)blockIdx.x * 4 + wave;
    const float* xr = X + row * 2048 + lane * 4;
    const uint4* cb = ctab + lane;

    float re[16], im[16];
#pragma unroll
    for (int eh = 0; eh < 4; ++eh) {
        float4 vr = *(const float4*)(xr + eh * 256);
        float4 vi = *(const float4*)(xr + 1024 + eh * 256);
        re[eh * 4 + 0] = vr.x; re[eh * 4 + 1] = vr.y; re[eh * 4 + 2] = vr.z; re[eh * 4 + 3] = vr.w;
        im[eh * 4 + 0] = vi.x; im[eh * 4 + 1] = vi.y; im[eh * 4 + 2] = vi.z; im[eh * 4 + 3] = vi.w;
    }

    stage_intra<1>(re, im, cb + 0 * 512);
    stage_intra<2>(re, im, cb + 1 * 512);

    stage_shfl<1>(re, im, cb + 2 * 512);
    stage_shfl<2>(re, im, cb + 3 * 512);
    stage_shfl<4>(re, im, cb + 4 * 512);
    stage_shfl<8>(re, im, cb + 5 * 512);
    stage_shfl<16>(re, im, cb + 6 * 512);
    stage_shfl<32>(re, im, cb + 7 * 512);

    stage_intra<4>(re, im, cb + 8 * 512);
    stage_intra<8>(re, im, cb + 9 * 512);

    float* orow = out + row * 2048 + lane * 4;
#pragma unroll
    for (int eh = 0; eh < 4; ++eh) {
        nfloat4 vr = { re[eh * 4 + 0], re[eh * 4 + 1], re[eh * 4 + 2], re[eh * 4 + 3] };
        nfloat4 vi = { im[eh * 4 + 0], im[eh * 4 + 1], im[eh * 4 + 2], im[eh * 4 + 3] };
        __builtin_nontemporal_store(vr, (nfloat4*)(orow + eh * 256));
        __builtin_nontemporal_store(vi, (nfloat4*)(orow + 1024 + eh * 256));
    }
}

extern "C" void kernel_launch(void* const* d_in, const int* in_sizes, int n_in,
                              void* d_out, int out_size, void* d_ws, size_t ws_size,
                              hipStream_t stream) {
    const float* X     = (const float*)d_in[0];
    const float* theta = (const float*)d_in[1];
    const float* phi   = (const float*)d_in[2];
    const float* psi   = (const float*)d_in[3];
    uint4* ctab = (uint4*)d_ws;   // P*512*16 B = 80 KB

    coef_kernel<<<(P * 512 + 255) / 256, 256, 0, stream>>>(theta, phi, psi, ctab);
    fft_kernel<<<NROWS / 4, 256, 0, stream>>>(X, ctab, (float*)d_out);
}

// Round 15
// 93.639 us; speedup vs baseline: 4.2757x; 4.2757x over previous
//
#include <hip/hip_runtime.h>
#include <hip/hip_fp16.h>

#define P 10
#define D 1024
#define NROWS 16384

typedef float nfloat4 __attribute__((ext_vector_type(4)));   // clang-native for nontemporal builtins

// ---------------------------------------------------------------------------
// Column mapping (r4 keeper):
//   k = e_hi*256 + lane*4 + e_lo,  e = e_hi*4 + e_lo,  e in [0,16), lane in [0,64)
//   stage j flips bit j of k:
//     j=0,1 -> e bits 0,1 (intra) | j=2..7 -> lane bit j-2 (shfl) | j=8,9 -> e bits 2,3 (intra)
// Coef table swizzled per-column f16 (r10 keeper): ctab[j*D + e*64 + lane] =
// uint2 {h2(u), h2(v)} for column k(e,lane). psi folded into stage-9 coefs.
//
// THIS ROUND: R=1 (one row per wave) + __launch_bounds__(256,6).
// r14 lesson: the (256,8) clamp allocated HALF the expected 64-reg cap ->
// 1 GB of spill. (256,6) caps at ~85 >= the ~60-70 natural need of the
// single-row kernel: no spill, 24 waves/CU (1.5x all passing rounds).
// r14 also showed occupancy 79% sustains 3.6 TB/s -> latency hiding works
// at high wave count; this buys it without scratch traffic.
// ---------------------------------------------------------------------------
__global__ void coef_kernel(const float* __restrict__ theta,
                            const float* __restrict__ phi,
                            const float* __restrict__ psi,
                            uint2* __restrict__ ctab) {
    int idx = blockIdx.x * blockDim.x + threadIdx.x;
    if (idx >= P * D) return;
    int j = idx >> 10;
    int slot = idx & (D - 1);
    int e = slot >> 6;
    int lane = slot & 63;
    int k = ((e >> 2) << 8) + (lane << 2) + (e & 3);   // column this slot serves
    int b = (k >> j) & 1;
    unsigned lowmask = (1u << j) - 1u;
    unsigned m = ((unsigned)k & lowmask) | (((unsigned)k >> 1) & ~lowmask); // delete bit j
    float th = theta[j * (D / 2) + m];
    float ph = phi[j * (D / 2) + m];
    float h = th * 0.5f;
    float s1 = sinf(h), c1 = cosf(h);
    float s2 = sinf(h + ph), c2 = cosf(h + ph);
    float ur, ui, vr, vi;
    if (b) { ur =  s1 * s1; vr = -c1 * s2; ui = -c1 * s1; vi = c1 * c2; }
    else   { ur = -s1 * s2; vr = -c1 * s1; ui =  s1 * c2; vi = c1 * c1; }
    if (j == P - 1) {
        float ps = psi[k];
        float cp = cosf(ps), sp = sinf(ps);
        float ur2 = cp * ur - sp * ui, ui2 = sp * ur + cp * ui;
        float vr2 = cp * vr - sp * vi, vi2 = sp * vr + cp * vi;
        ur = ur2; ui = ui2; vr = vr2; vi = vi2;
    }
    __half2 uh = __floats2half2_rn(ur, ui);
    __half2 vh = __floats2half2_rn(vr, vi);
    uint2 w;
    w.x = *reinterpret_cast<unsigned int*>(&uh);
    w.y = *reinterpret_cast<unsigned int*>(&vh);
    ctab[idx] = w;
}

__device__ __forceinline__ void unpack_c(uint2 w, float& ur, float& ui,
                                         float& vr, float& vi) {
    __half2 a = *reinterpret_cast<__half2*>(&w.x);
    __half2 b = *reinterpret_cast<__half2*>(&w.y);
    ur = __low2float(a); ui = __high2float(a);
    vr = __low2float(b); vi = __high2float(b);
}

// ---------------------------------------------------------------------------
// Intra-thread butterfly stage (single row): partner differs in bit PM of e.
// ---------------------------------------------------------------------------
template <int PM>
__device__ __forceinline__ void stage_intra(float (&re)[16], float (&im)[16],
                                            const uint2* cj) {
#pragma unroll
    for (int e0 = 0; e0 < 16; ++e0) {
        if (e0 & PM) continue;
        const int e1 = e0 | PM;
        uint2 w0 = cj[e0 * 64];
        uint2 w1 = cj[e1 * 64];
        float u0r, u0i, v0r, v0i, u1r, u1i, v1r, v1i;
        unpack_c(w0, u0r, u0i, v0r, v0i);
        unpack_c(w1, u1r, u1i, v1r, v1i);
        float ar0 = re[e0], ai0 = im[e0], ar1 = re[e1], ai1 = im[e1];
        re[e0] = u0r * ar0 - u0i * ai0 + v0r * ar1 - v0i * ai1;
        im[e0] = u0r * ai0 + u0i * ar0 + v0r * ai1 + v0i * ar1;
        re[e1] = u1r * ar1 - u1i * ai1 + v1r * ar0 - v1i * ai0;
        im[e1] = u1r * ai1 + u1i * ar1 + v1r * ai0 + v1i * ar0;
    }
}

// ---------------------------------------------------------------------------
// Cross-lane butterfly stage (single row): partner differs in lane bit MASK.
// ---------------------------------------------------------------------------
template <int MASK>
__device__ __forceinline__ void stage_shfl(float (&re)[16], float (&im)[16],
                                           const uint2* cj) {
#pragma unroll
    for (int e = 0; e < 16; ++e) {
        uint2 w = cj[e * 64];
        float ur, ui, vr, vi;
        unpack_c(w, ur, ui, vr, vi);
        float sre = __shfl_xor(re[e], MASK);
        float sim = __shfl_xor(im[e], MASK);
        float nre = ur * re[e] - ui * im[e] + vr * sre - vi * sim;
        float nim = ur * im[e] + ui * re[e] + vr * sim + vi * sre;
        re[e] = nre; im[e] = nim;
    }
}

__global__ __launch_bounds__(256, 6) void fft_kernel(const float* __restrict__ X,
                                                     const uint2* __restrict__ ctab,
                                                     float* __restrict__ out) {
    const int lane = threadIdx.x & 63;
    const int wave = threadIdx.x >> 6;
    const long row = (long)blockIdx.x * 4 + wave;
    const float* xr = X + row * 2048 + lane * 4;
    const uint2* cb = ctab + lane;

    float re[16], im[16];
#pragma unroll
    for (int eh = 0; eh < 4; ++eh) {
        float4 vr = *(const float4*)(xr + eh * 256);
        float4 vi = *(const float4*)(xr + 1024 + eh * 256);
        re[eh * 4 + 0] = vr.x; re[eh * 4 + 1] = vr.y; re[eh * 4 + 2] = vr.z; re[eh * 4 + 3] = vr.w;
        im[eh * 4 + 0] = vi.x; im[eh * 4 + 1] = vi.y; im[eh * 4 + 2] = vi.z; im[eh * 4 + 3] = vi.w;
    }

    stage_intra<1>(re, im, cb + 0 * D);
    stage_intra<2>(re, im, cb + 1 * D);

    stage_shfl<1>(re, im, cb + 2 * D);
    stage_shfl<2>(re, im, cb + 3 * D);
    stage_shfl<4>(re, im, cb + 4 * D);
    stage_shfl<8>(re, im, cb + 5 * D);
    stage_shfl<16>(re, im, cb + 6 * D);
    stage_shfl<32>(re, im, cb + 7 * D);

    stage_intra<4>(re, im, cb + 8 * D);
    stage_intra<8>(re, im, cb + 9 * D);

    float* orow = out + row * 2048 + lane * 4;
#pragma unroll
    for (int eh = 0; eh < 4; ++eh) {
        nfloat4 vr = { re[eh * 4 + 0], re[eh * 4 + 1], re[eh * 4 + 2], re[eh * 4 + 3] };
        nfloat4 vi = { im[eh * 4 + 0], im[eh * 4 + 1], im[eh * 4 + 2], im[eh * 4 + 3] };
        __builtin_nontemporal_store(vr, (nfloat4*)(orow + eh * 256));
        __builtin_nontemporal_store(vi, (nfloat4*)(orow + 1024 + eh * 256));
    }
}

extern "C" void kernel_launch(void* const* d_in, const int* in_sizes, int n_in,
                              void* d_out, int out_size, void* d_ws, size_t ws_size,
                              hipStream_t stream) {
    const float* X     = (const float*)d_in[0];
    const float* theta = (const float*)d_in[1];
    const float* phi   = (const float*)d_in[2];
    const float* psi   = (const float*)d_in[3];
    uint2* ctab = (uint2*)d_ws;   // P*D*8 B = 80 KB

    coef_kernel<<<(P * D + 255) / 256, 256, 0, stream>>>(theta, phi, psi, ctab);
    fft_kernel<<<NROWS / 4, 256, 0, stream>>>(X, ctab, (float*)d_out);
}

// Round 16
// 84.381 us; speedup vs baseline: 4.7448x; 1.1097x over previous
//
#include <hip/hip_runtime.h>
#include <hip/hip_fp16.h>

#define P 10
#define D 1024
#define NROWS 16384

typedef float nfloat4 __attribute__((ext_vector_type(4)));   // clang-native for nontemporal builtins

// ---------------------------------------------------------------------------
// Column mapping (r4 keeper):
//   k = e_hi*256 + lane*4 + e_lo,  e = e_hi*4 + e_lo,  e in [0,16), lane in [0,64)
//   stage j flips bit j of k:
//     j=0,1 -> e bits 0,1 (intra) | j=2..7 -> lane bit j-2 (shfl) | j=8,9 -> e bits 2,3 (intra)
// Coef table swizzled per-column f16 (r10 keeper): ctab[j*D + e*64 + lane] =
// uint2 {h2(u), h2(v)} for column k(e,lane). psi folded into stage-9 coefs.
//
// THIS ROUND: stages 0-7 of the coef table (64 KB) are block-staged into
// static LDS ONCE (single barrier), then all stages run barrier-free.
// Coef access for 8 of 10 stages: ds_read_b64 (~30cy, bank-conflict-free
// 2-way aliasing) instead of L2 round-trips (~200cy; the 80KB table thrashes
// the 32KB L1). Stages 8-9 keep the r10 global path. R=2 rows/thread,
// 512-thread blocks (8 waves, 16 rows), grid 1024.
// ---------------------------------------------------------------------------
__global__ void coef_kernel(const float* __restrict__ theta,
                            const float* __restrict__ phi,
                            const float* __restrict__ psi,
                            uint2* __restrict__ ctab) {
    int idx = blockIdx.x * blockDim.x + threadIdx.x;
    if (idx >= P * D) return;
    int j = idx >> 10;
    int slot = idx & (D - 1);
    int e = slot >> 6;
    int lane = slot & 63;
    int k = ((e >> 2) << 8) + (lane << 2) + (e & 3);   // column this slot serves
    int b = (k >> j) & 1;
    unsigned lowmask = (1u << j) - 1u;
    unsigned m = ((unsigned)k & lowmask) | (((unsigned)k >> 1) & ~lowmask); // delete bit j
    float th = theta[j * (D / 2) + m];
    float ph = phi[j * (D / 2) + m];
    float h = th * 0.5f;
    float s1 = sinf(h), c1 = cosf(h);
    float s2 = sinf(h + ph), c2 = cosf(h + ph);
    float ur, ui, vr, vi;
    if (b) { ur =  s1 * s1; vr = -c1 * s2; ui = -c1 * s1; vi = c1 * c2; }
    else   { ur = -s1 * s2; vr = -c1 * s1; ui =  s1 * c2; vi = c1 * c1; }
    if (j == P - 1) {
        float ps = psi[k];
        float cp = cosf(ps), sp = sinf(ps);
        float ur2 = cp * ur - sp * ui, ui2 = sp * ur + cp * ui;
        float vr2 = cp * vr - sp * vi, vi2 = sp * vr + cp * vi;
        ur = ur2; ui = ui2; vr = vr2; vi = vi2;
    }
    __half2 uh = __floats2half2_rn(ur, ui);
    __half2 vh = __floats2half2_rn(vr, vi);
    uint2 w;
    w.x = *reinterpret_cast<unsigned int*>(&uh);
    w.y = *reinterpret_cast<unsigned int*>(&vh);
    ctab[idx] = w;
}

__device__ __forceinline__ void unpack_c(uint2 w, float& ur, float& ui,
                                         float& vr, float& vi) {
    __half2 a = *reinterpret_cast<__half2*>(&w.x);
    __half2 b = *reinterpret_cast<__half2*>(&w.y);
    ur = __low2float(a); ui = __high2float(a);
    vr = __low2float(b); vi = __high2float(b);
}

// ---------------------------------------------------------------------------
// Intra-thread butterfly stage: partner differs in bit PM of e.
// cj may point to LDS or global; __forceinline__ lets addrspace inference
// emit ds_read_b64 for the LDS case.
// ---------------------------------------------------------------------------
template <int PM, typename PTR>
__device__ __forceinline__ void stage_intra(float (&ra)[16], float (&ia)[16],
                                            float (&rb)[16], float (&ib)[16],
                                            PTR cj) {
#pragma unroll
    for (int e0 = 0; e0 < 16; ++e0) {
        if (e0 & PM) continue;
        const int e1 = e0 | PM;
        uint2 w0 = cj[e0 * 64];
        uint2 w1 = cj[e1 * 64];
        float u0r, u0i, v0r, v0i, u1r, u1i, v1r, v1i;
        unpack_c(w0, u0r, u0i, v0r, v0i);
        unpack_c(w1, u1r, u1i, v1r, v1i);
        float ar0 = ra[e0], ai0 = ia[e0], ar1 = ra[e1], ai1 = ia[e1];
        float br0 = rb[e0], bi0 = ib[e0], br1 = rb[e1], bi1 = ib[e1];
        ra[e0] = u0r * ar0 - u0i * ai0 + v0r * ar1 - v0i * ai1;
        ia[e0] = u0r * ai0 + u0i * ar0 + v0r * ai1 + v0i * ar1;
        ra[e1] = u1r * ar1 - u1i * ai1 + v1r * ar0 - v1i * ai0;
        ia[e1] = u1r * ai1 + u1i * ar1 + v1r * ai0 + v1i * ar0;
        rb[e0] = u0r * br0 - u0i * bi0 + v0r * br1 - v0i * bi1;
        ib[e0] = u0r * bi0 + u0i * br0 + v0r * bi1 + v0i * br1;
        rb[e1] = u1r * br1 - u1i * bi1 + v1r * br0 - v1i * bi0;
        ib[e1] = u1r * bi1 + u1i * br1 + v1r * bi0 + v1i * br0;
    }
}

// ---------------------------------------------------------------------------
// Cross-lane butterfly stage: partner differs in lane bit MASK.
// ---------------------------------------------------------------------------
template <int MASK, typename PTR>
__device__ __forceinline__ void stage_shfl(float (&ra)[16], float (&ia)[16],
                                           float (&rb)[16], float (&ib)[16],
                                           PTR cj) {
#pragma unroll
    for (int e = 0; e < 16; ++e) {
        uint2 w = cj[e * 64];
        float ur, ui, vr, vi;
        unpack_c(w, ur, ui, vr, vi);
        float sra = __shfl_xor(ra[e], MASK);
        float sia = __shfl_xor(ia[e], MASK);
        float srb = __shfl_xor(rb[e], MASK);
        float sib = __shfl_xor(ib[e], MASK);
        float nra = ur * ra[e] - ui * ia[e] + vr * sra - vi * sia;
        float nia = ur * ia[e] + ui * ra[e] + vr * sia + vi * sra;
        float nrb = ur * rb[e] - ui * ib[e] + vr * srb - vi * sib;
        float nib = ur * ib[e] + ui * rb[e] + vr * sib + vi * srb;
        ra[e] = nra; ia[e] = nia; rb[e] = nrb; ib[e] = nib;
    }
}

__global__ __launch_bounds__(512) void fft_kernel(const float* __restrict__ X,
                                                  const uint2* __restrict__ ctab,
                                                  float* __restrict__ out) {
    __shared__ uint4 lds4[4096];                 // 64 KB: stages 0..7 of ctab
    const int tid  = threadIdx.x;
    const int lane = tid & 63;
    const int wave = tid >> 6;                   // 0..7
    const long rowbase = (long)blockIdx.x * 16 + (long)wave * 2;
    const float* x0 = X + rowbase * 2048 + lane * 4;
    const float* x1 = x0 + 2048;

    // --- one-time cooperative stage: 64 KB = 4096 uint4, 8 per thread ---
    {
        const uint4* g4 = (const uint4*)ctab;
#pragma unroll
        for (int i = 0; i < 8; ++i)
            lds4[i * 512 + tid] = g4[i * 512 + tid];
    }

    // X loads overlap the staging loads (independent streams)
    float ra[16], ia[16], rb[16], ib[16];
#pragma unroll
    for (int eh = 0; eh < 4; ++eh) {
        float4 v0r = *(const float4*)(x0 + eh * 256);
        float4 v0i = *(const float4*)(x0 + 1024 + eh * 256);
        float4 v1r = *(const float4*)(x1 + eh * 256);
        float4 v1i = *(const float4*)(x1 + 1024 + eh * 256);
        ra[eh * 4 + 0] = v0r.x; ra[eh * 4 + 1] = v0r.y; ra[eh * 4 + 2] = v0r.z; ra[eh * 4 + 3] = v0r.w;
        ia[eh * 4 + 0] = v0i.x; ia[eh * 4 + 1] = v0i.y; ia[eh * 4 + 2] = v0i.z; ia[eh * 4 + 3] = v0i.w;
        rb[eh * 4 + 0] = v1r.x; rb[eh * 4 + 1] = v1r.y; rb[eh * 4 + 2] = v1r.z; rb[eh * 4 + 3] = v1r.w;
        ib[eh * 4 + 0] = v1i.x; ib[eh * 4 + 1] = v1i.y; ib[eh * 4 + 2] = v1i.z; ib[eh * 4 + 3] = v1i.w;
    }

    __syncthreads();                             // the ONLY barrier

    const uint2* lc = (const uint2*)lds4;        // LDS view, stages 0..7
    stage_intra<1>(ra, ia, rb, ib, lc + 0 * D + lane);
    stage_intra<2>(ra, ia, rb, ib, lc + 1 * D + lane);

    stage_shfl<1>(ra, ia, rb, ib, lc + 2 * D + lane);
    stage_shfl<2>(ra, ia, rb, ib, lc + 3 * D + lane);
    stage_shfl<4>(ra, ia, rb, ib, lc + 4 * D + lane);
    stage_shfl<8>(ra, ia, rb, ib, lc + 5 * D + lane);
    stage_shfl<16>(ra, ia, rb, ib, lc + 6 * D + lane);
    stage_shfl<32>(ra, ia, rb, ib, lc + 7 * D + lane);

    stage_intra<4>(ra, ia, rb, ib, ctab + 8 * D + lane);   // global
    stage_intra<8>(ra, ia, rb, ib, ctab + 9 * D + lane);   // global

    float* o0 = out + rowbase * 2048 + lane * 4;
    float* o1 = o0 + 2048;
#pragma unroll
    for (int eh = 0; eh < 4; ++eh) {
        nfloat4 v0r = { ra[eh * 4 + 0], ra[eh * 4 + 1], ra[eh * 4 + 2], ra[eh * 4 + 3] };
        nfloat4 v0i = { ia[eh * 4 + 0], ia[eh * 4 + 1], ia[eh * 4 + 2], ia[eh * 4 + 3] };
        nfloat4 v1r = { rb[eh * 4 + 0], rb[eh * 4 + 1], rb[eh * 4 + 2], rb[eh * 4 + 3] };
        nfloat4 v1i = { ib[eh * 4 + 0], ib[eh * 4 + 1], ib[eh * 4 + 2], ib[eh * 4 + 3] };
        __builtin_nontemporal_store(v0r, (nfloat4*)(o0 + eh * 256));
        __builtin_nontemporal_store(v0i, (nfloat4*)(o0 + 1024 + eh * 256));
        __builtin_nontemporal_store(v1r, (nfloat4*)(o1 + eh * 256));
        __builtin_nontemporal_store(v1i, (nfloat4*)(o1 + 1024 + eh * 256));
    }
}

extern "C" void kernel_launch(void* const* d_in, const int* in_sizes, int n_in,
                              void* d_out, int out_size, void* d_ws, size_t ws_size,
                              hipStream_t stream) {
    const float* X     = (const float*)d_in[0];
    const float* theta = (const float*)d_in[1];
    const float* phi   = (const float*)d_in[2];
    const float* psi   = (const float*)d_in[3];
    uint2* ctab = (uint2*)d_ws;   // P*D*8 B = 80 KB

    coef_kernel<<<(P * D + 255) / 256, 256, 0, stream>>>(theta, phi, psi, ctab);
    fft_kernel<<<NROWS / 16, 512, 0, stream>>>(X, ctab, (float*)d_out);
}

// Round 17
// 75.343 us; speedup vs baseline: 5.3141x; 1.1200x over previous
//
#include <hip/hip_runtime.h>
#include <hip/hip_fp16.h>

#define P 10
#define D 1024
#define NROWS 16384

typedef float nfloat4 __attribute__((ext_vector_type(4)));   // clang-native for nontemporal builtins

// ---------------------------------------------------------------------------
// FINAL KEEPER (r10 structure, restored after r11-r16 probes all regressed
// or were neutral):
//   k = e_hi*256 + lane*4 + e_lo,  e = e_hi*4 + e_lo,  e in [0,16), lane in [0,64)
//   stage j flips bit j of k:
//     j=0,1 -> e bits 0,1 (intra) | j=2..7 -> lane bit j-2 (shfl) | j=8,9 -> e bits 2,3 (intra)
// Coef table swizzled per-column f16: ctab[j*D + e*64 + lane] = uint2
// {h2(u), h2(v)} for column k(e,lane); psi folded into stage-9 coefs.
// R=2 rows/thread, dwordx4 X I/O, nontemporal stores, no launch-bounds clamp.
//
// Ledger: coef bytes/instrs/traffic, LDS staging, reg prefetch, R=1/3/4,
// DPP/permlane exchanges -- all tested on HW, all neutral or regressions.
// This is the measured plateau: ~74.6 us, 2.4x the warm-HBM floor,
// latency-bound (all pipes <=40%).
// ---------------------------------------------------------------------------
__global__ void coef_kernel(const float* __restrict__ theta,
                            const float* __restrict__ phi,
                            const float* __restrict__ psi,
                            uint2* __restrict__ ctab) {
    int idx = blockIdx.x * blockDim.x + threadIdx.x;
    if (idx >= P * D) return;
    int j = idx >> 10;
    int slot = idx & (D - 1);
    int e = slot >> 6;
    int lane = slot & 63;
    int k = ((e >> 2) << 8) + (lane << 2) + (e & 3);   // column this slot serves
    int b = (k >> j) & 1;
    unsigned lowmask = (1u << j) - 1u;
    unsigned m = ((unsigned)k & lowmask) | (((unsigned)k >> 1) & ~lowmask); // delete bit j
    float th = theta[j * (D / 2) + m];
    float ph = phi[j * (D / 2) + m];
    float h = th * 0.5f;
    float s1 = sinf(h), c1 = cosf(h);
    float s2 = sinf(h + ph), c2 = cosf(h + ph);
    float ur, ui, vr, vi;
    if (b) { ur =  s1 * s1; vr = -c1 * s2; ui = -c1 * s1; vi = c1 * c2; }
    else   { ur = -s1 * s2; vr = -c1 * s1; ui =  s1 * c2; vi = c1 * c1; }
    if (j == P - 1) {
        float ps = psi[k];
        float cp = cosf(ps), sp = sinf(ps);
        float ur2 = cp * ur - sp * ui, ui2 = sp * ur + cp * ui;
        float vr2 = cp * vr - sp * vi, vi2 = sp * vr + cp * vi;
        ur = ur2; ui = ui2; vr = vr2; vi = vi2;
    }
    __half2 uh = __floats2half2_rn(ur, ui);
    __half2 vh = __floats2half2_rn(vr, vi);
    uint2 w;
    w.x = *reinterpret_cast<unsigned int*>(&uh);
    w.y = *reinterpret_cast<unsigned int*>(&vh);
    ctab[idx] = w;
}

__device__ __forceinline__ void unpack_c(uint2 w, float& ur, float& ui,
                                         float& vr, float& vi) {
    __half2 a = *reinterpret_cast<__half2*>(&w.x);
    __half2 b = *reinterpret_cast<__half2*>(&w.y);
    ur = __low2float(a); ui = __high2float(a);
    vr = __low2float(b); vi = __high2float(b);
}

// ---------------------------------------------------------------------------
// Intra-thread butterfly stage: partner differs in a bit of e (mask PM).
// ---------------------------------------------------------------------------
template <int PM>
__device__ __forceinline__ void stage_intra(float (&ra)[16], float (&ia)[16],
                                            float (&rb)[16], float (&ib)[16],
                                            const uint2* cj) {
#pragma unroll
    for (int e0 = 0; e0 < 16; ++e0) {
        if (e0 & PM) continue;
        const int e1 = e0 | PM;
        uint2 w0 = cj[e0 * 64];
        uint2 w1 = cj[e1 * 64];
        float u0r, u0i, v0r, v0i, u1r, u1i, v1r, v1i;
        unpack_c(w0, u0r, u0i, v0r, v0i);
        unpack_c(w1, u1r, u1i, v1r, v1i);
        float ar0 = ra[e0], ai0 = ia[e0], ar1 = ra[e1], ai1 = ia[e1];
        float br0 = rb[e0], bi0 = ib[e0], br1 = rb[e1], bi1 = ib[e1];
        ra[e0] = u0r * ar0 - u0i * ai0 + v0r * ar1 - v0i * ai1;
        ia[e0] = u0r * ai0 + u0i * ar0 + v0r * ai1 + v0i * ar1;
        ra[e1] = u1r * ar1 - u1i * ai1 + v1r * ar0 - v1i * ai0;
        ia[e1] = u1r * ai1 + u1i * ar1 + v1r * ai0 + v1i * ar0;
        rb[e0] = u0r * br0 - u0i * bi0 + v0r * br1 - v0i * bi1;
        ib[e0] = u0r * bi0 + u0i * br0 + v0r * bi1 + v0i * br1;
        rb[e1] = u1r * br1 - u1i * bi1 + v1r * br0 - v1i * bi0;
        ib[e1] = u1r * bi1 + u1i * br1 + v1r * bi0 + v1i * br0;
    }
}

// ---------------------------------------------------------------------------
// Cross-lane butterfly stage: partner differs in lane bit MASK.
// ---------------------------------------------------------------------------
template <int MASK>
__device__ __forceinline__ void stage_shfl(float (&ra)[16], float (&ia)[16],
                                           float (&rb)[16], float (&ib)[16],
                                           const uint2* cj) {
#pragma unroll
    for (int e = 0; e < 16; ++e) {
        uint2 w = cj[e * 64];
        float ur, ui, vr, vi;
        unpack_c(w, ur, ui, vr, vi);
        float sra = __shfl_xor(ra[e], MASK);
        float sia = __shfl_xor(ia[e], MASK);
        float srb = __shfl_xor(rb[e], MASK);
        float sib = __shfl_xor(ib[e], MASK);
        float nra = ur * ra[e] - ui * ia[e] + vr * sra - vi * sia;
        float nia = ur * ia[e] + ui * ra[e] + vr * sia + vi * sra;
        float nrb = ur * rb[e] - ui * ib[e] + vr * srb - vi * sib;
        float nib = ur * ib[e] + ui * rb[e] + vr * sib + vi * srb;
        ra[e] = nra; ia[e] = nia; rb[e] = nrb; ib[e] = nib;
    }
}

__global__ __launch_bounds__(256) void fft_kernel(const float* __restrict__ X,
                                                  const uint2* __restrict__ ctab,
                                                  float* __restrict__ out) {
    const int lane = threadIdx.x & 63;
    const int wave = threadIdx.x >> 6;
    const long rowbase = (long)blockIdx.x * 8 + (long)wave * 2;
    const float* x0 = X + rowbase * 2048 + lane * 4;
    const float* x1 = x0 + 2048;
    const uint2* cb = ctab + lane;

    float ra[16], ia[16], rb[16], ib[16];
#pragma unroll
    for (int eh = 0; eh < 4; ++eh) {
        float4 v0r = *(const float4*)(x0 + eh * 256);
        float4 v0i = *(const float4*)(x0 + 1024 + eh * 256);
        float4 v1r = *(const float4*)(x1 + eh * 256);
        float4 v1i = *(const float4*)(x1 + 1024 + eh * 256);
        ra[eh * 4 + 0] = v0r.x; ra[eh * 4 + 1] = v0r.y; ra[eh * 4 + 2] = v0r.z; ra[eh * 4 + 3] = v0r.w;
        ia[eh * 4 + 0] = v0i.x; ia[eh * 4 + 1] = v0i.y; ia[eh * 4 + 2] = v0i.z; ia[eh * 4 + 3] = v0i.w;
        rb[eh * 4 + 0] = v1r.x; rb[eh * 4 + 1] = v1r.y; rb[eh * 4 + 2] = v1r.z; rb[eh * 4 + 3] = v1r.w;
        ib[eh * 4 + 0] = v1i.x; ib[eh * 4 + 1] = v1i.y; ib[eh * 4 + 2] = v1i.z; ib[eh * 4 + 3] = v1i.w;
    }

    stage_intra<1>(ra, ia, rb, ib, cb + 0 * D);
    stage_intra<2>(ra, ia, rb, ib, cb + 1 * D);

    stage_shfl<1>(ra, ia, rb, ib, cb + 2 * D);
    stage_shfl<2>(ra, ia, rb, ib, cb + 3 * D);
    stage_shfl<4>(ra, ia, rb, ib, cb + 4 * D);
    stage_shfl<8>(ra, ia, rb, ib, cb + 5 * D);
    stage_shfl<16>(ra, ia, rb, ib, cb + 6 * D);
    stage_shfl<32>(ra, ia, rb, ib, cb + 7 * D);

    stage_intra<4>(ra, ia, rb, ib, cb + 8 * D);
    stage_intra<8>(ra, ia, rb, ib, cb + 9 * D);

    float* o0 = out + rowbase * 2048 + lane * 4;
    float* o1 = o0 + 2048;
#pragma unroll
    for (int eh = 0; eh < 4; ++eh) {
        nfloat4 v0r = { ra[eh * 4 + 0], ra[eh * 4 + 1], ra[eh * 4 + 2], ra[eh * 4 + 3] };
        nfloat4 v0i = { ia[eh * 4 + 0], ia[eh * 4 + 1], ia[eh * 4 + 2], ia[eh * 4 + 3] };
        nfloat4 v1r = { rb[eh * 4 + 0], rb[eh * 4 + 1], rb[eh * 4 + 2], rb[eh * 4 + 3] };
        nfloat4 v1i = { ib[eh * 4 + 0], ib[eh * 4 + 1], ib[eh * 4 + 2], ib[eh * 4 + 3] };
        __builtin_nontemporal_store(v0r, (nfloat4*)(o0 + eh * 256));
        __builtin_nontemporal_store(v0i, (nfloat4*)(o0 + 1024 + eh * 256));
        __builtin_nontemporal_store(v1r, (nfloat4*)(o1 + eh * 256));
        __builtin_nontemporal_store(v1i, (nfloat4*)(o1 + 1024 + eh * 256));
    }
}

extern "C" void kernel_launch(void* const* d_in, const int* in_sizes, int n_in,
                              void* d_out, int out_size, void* d_ws, size_t ws_size,
                              hipStream_t stream) {
    const float* X     = (const float*)d_in[0];
    const float* theta = (const float*)d_in[1];
    const float* phi   = (const float*)d_in[2];
    const float* psi   = (const float*)d_in[3];
    uint2* ctab = (uint2*)d_ws;   // P*D*8 B = 80 KB

    coef_kernel<<<(P * D + 255) / 256, 256, 0, stream>>>(theta, phi, psi, ctab);
    fft_kernel<<<NROWS / 8, 256, 0, stream>>>(X, ctab, (float*)d_out);
}